// Round 8
// baseline (275.541 us; speedup 1.0000x reference)
//
#include <hip/hip_runtime.h>

// OccupancyToTopology: for each of 64^3 cells, emit the 256-entry
// tensor-product table over its 8 corner occupancy probabilities.
//
// One 64-lane wave per cell; lane i owns t = 4i..4i+3:
//   bits 2..7 of t == bits 0..5 of lane -> 6-factor base product
//   bits 0..1 of t -> four p0/p1 combos -> one float4 store
// Wave writes the cell's contiguous 1 KiB row fully coalesced.
//
// Perf-critical details:
//  - Corner addresses are wave-uniform: readfirstlane forces the base into
//    an SGPR so the loads become s_load (lgkmcnt), leaving the VMEM pipe
//    (vmcnt) exclusively for the output store stream. Without this, the
//    compiler's vmcnt(0) before consuming the loads also drains the previous
//    store -> ~1 store in flight -> 2.4 TB/s observed in R2.
//  - 2-cell unroll: loads for both cells issued before either store.
//  - Nontemporal stores: don't evict the 1 MB input from L2.
//    NOTE: __builtin_nontemporal_store requires a clang ext_vector_type,
//    not HIP's float4 class (R6 compile error).

typedef float vfloat4 __attribute__((ext_vector_type(4)));

struct Corners { float p[8]; };

__device__ __forceinline__ Corners load_cell(const float* __restrict__ occ, int cell)
{
    const int S1 = 65, S2 = 65 * 65;
    int z = cell & 63;
    int y = (cell >> 6) & 63;
    int x = cell >> 12;
    // wave-uniform -> SGPR base -> scalar (SMEM) loads
    int base = __builtin_amdgcn_readfirstlane(x * S2 + y * S1 + z);
    const float* c = occ + base;
    Corners r;
    // CORNER_OFFSETS: c0(0,0,0) c1(1,0,0) c2(1,1,0) c3(0,1,0)
    //                 c4(0,0,1) c5(1,0,1) c6(1,1,1) c7(0,1,1)
    r.p[0] = c[0];           r.p[4] = c[1];            // (0,0,0) (0,0,1)
    r.p[3] = c[S1];          r.p[7] = c[S1 + 1];       // (0,1,0) (0,1,1)
    r.p[1] = c[S2];          r.p[5] = c[S2 + 1];       // (1,0,0) (1,0,1)
    r.p[2] = c[S2 + S1];     r.p[6] = c[S2 + S1 + 1];  // (1,1,0) (1,1,1)
    return r;
}

__device__ __forceinline__ void emit_cell(const Corners& cr, int lane,
                                          float* __restrict__ out, int cell)
{
    float p0 = cr.p[0], p1 = cr.p[1], p2 = cr.p[2], p3 = cr.p[3];
    float p4 = cr.p[4], p5 = cr.p[5], p6 = cr.p[6], p7 = cr.p[7];

    float f2 = (lane & 1)  ? p2 : 1.0f - p2;
    float f3 = (lane & 2)  ? p3 : 1.0f - p3;
    float f4 = (lane & 4)  ? p4 : 1.0f - p4;
    float f5 = (lane & 8)  ? p5 : 1.0f - p5;
    float f6 = (lane & 16) ? p6 : 1.0f - p6;
    float f7 = (lane & 32) ? p7 : 1.0f - p7;
    float bp = ((f2 * f3) * (f4 * f5)) * (f6 * f7);

    float q0 = 1.0f - p0;
    float q1 = 1.0f - p1;
    vfloat4 v;
    v.x = bp * (q0 * q1);   // t bits (0,0)
    v.y = bp * (p0 * q1);   // t bits (1,0)
    v.z = bp * (q0 * p1);   // t bits (0,1)
    v.w = bp * (p0 * p1);   // t bits (1,1)

    vfloat4* outp = reinterpret_cast<vfloat4*>(out + (size_t)cell * 256) + lane;
    __builtin_nontemporal_store(v, outp);
}

__global__ __launch_bounds__(256) void
occ_topo_kernel(const float* __restrict__ occ, float* __restrict__ out, int n_cells)
{
    const int lane        = threadIdx.x & 63;
    const int waveInBlk   = threadIdx.x >> 6;
    const int wavesPerBlk = blockDim.x >> 6;            // 4
    const int totalWaves  = gridDim.x * wavesPerBlk;    // 8192
    int wave_id = blockIdx.x * wavesPerBlk + waveInBlk;

    int cell = wave_id;
    // paired grid-stride: 262144 / 8192 = 32 cells/wave = 16 exact pairs
    for (; cell + totalWaves < n_cells; cell += 2 * totalWaves) {
        Corners a = load_cell(occ, cell);
        Corners b = load_cell(occ, cell + totalWaves);
        emit_cell(a, lane, out, cell);
        emit_cell(b, lane, out, cell + totalWaves);
    }
    if (cell < n_cells) {           // tail (not taken for 64^3 @ 8192 waves)
        Corners a = load_cell(occ, cell);
        emit_cell(a, lane, out, cell);
    }
}

extern "C" void kernel_launch(void* const* d_in, const int* in_sizes, int n_in,
                              void* d_out, int out_size, void* d_ws, size_t ws_size,
                              hipStream_t stream)
{
    const float* occ = (const float*)d_in[0];
    float* out = (float*)d_out;
    const int n_cells = 64 * 64 * 64;

    const int block = 256;   // 4 waves/block
    const int grid  = 2048;  // 8192 waves total, 32 cells each
    occ_topo_kernel<<<grid, block, 0, stream>>>(occ, out, n_cells);
}